// Round 16
// baseline (496.423 us; speedup 1.0000x reference)
//
#include <hip/hip_runtime.h>
#include <hip/hip_bf16.h>

// Shapes (fixed): B=128, F=8, K=256, D=256, H=256, HFF=512, L=2, M_PREV=2
#define B_   128
#define F_   8
#define K_   256
#define D_   256
#define H_   256
#define HFF_ 512
#define RT   64   // candidates per block

typedef _Float16 half8  __attribute__((ext_vector_type(8)));  // f16x8 MFMA frag
typedef _Float16 half4v __attribute__((ext_vector_type(4)));
typedef float floatx4   __attribute__((ext_vector_type(4)));  // MFMA acc

#define MFMAH(a,b,c) __builtin_amdgcn_mfma_f32_16x16x32_f16(a,b,c,0,0,0)

// R25 = R24 (best verified 485.5us) + deeper load-issue unrolling in the
// latency-bound side kernels: k_resfin GEMV loops unroll 4->8, k_prep heavy
// chains unroll 4->8. #pragma unroll does not reassociate accumulator
// chains -> bitwise-identical outputs. k_main byte-frozen (336us verified).
#define HA_S  260
#define HMA_S 132

// ---------------------------------------------------------------------------
// Fused prep — (h0->u->pre_u), (v->pre_v), and the fp16 weight shuffle.
__global__ void k_prep(const float* __restrict__ cb, const float* __restrict__ Win,
                       const float* __restrict__ bin, const float* __restrict__ Wcat,
                       const float* __restrict__ bcat, const float* __restrict__ xhat,
                       const float* __restrict__ W1, const float* __restrict__ b1,
                       const float* __restrict__ W2, const float* __restrict__ Wout,
                       float* __restrict__ u, float* __restrict__ v,
                       _Float16* __restrict__ w1f, _Float16* __restrict__ w2f,
                       _Float16* __restrict__ wof,
                       _Float16* __restrict__ pre_u, _Float16* __restrict__ pre_v) {
  const int blk = blockIdx.x, t = threadIdx.x;
  if (blk < K_) {
    __shared__ float row[D_];
    __shared__ float h0row[H_];
    __shared__ float urow[H_];
    row[t] = cb[blk * D_ + t];
    __syncthreads();
    float a0 = 0.f, a1 = 0.f, a2 = 0.f, a3 = 0.f;
    #pragma unroll 8
    for (int i = 0; i < 64; ++i) {
      a0 = fmaf(row[i      ], Win[(i      ) * H_ + t], a0);
      a1 = fmaf(row[i +  64], Win[(i +  64) * H_ + t], a1);
      a2 = fmaf(row[i + 128], Win[(i + 128) * H_ + t], a2);
      a3 = fmaf(row[i + 192], Win[(i + 192) * H_ + t], a3);
    }
    h0row[t] = bin[t] + ((a0 + a1) + (a2 + a3));
    __syncthreads();
    float c0 = 0.f, c1 = 0.f, c2 = 0.f, c3 = 0.f;
    #pragma unroll 8
    for (int i = 0; i < 64; ++i) {
      c0 = fmaf(h0row[i      ], Wcat[(i      ) * H_ + t], c0);
      c1 = fmaf(h0row[i +  64], Wcat[(i +  64) * H_ + t], c1);
      c2 = fmaf(h0row[i + 128], Wcat[(i + 128) * H_ + t], c2);
      c3 = fmaf(h0row[i + 192], Wcat[(i + 192) * H_ + t], c3);
    }
    const float uv = (c0 + c1) + (c2 + c3);
    u[blk * H_ + t] = uv;
    urow[t] = uv;
    __syncthreads();
    // fused pre_u[blk] = urow @ W1_0 (same 8-acc chain as old k_prep2)
    float p0 = 0.f, p1 = 0.f, p2 = 0.f, p3 = 0.f;
    float q0 = 0.f, q1 = 0.f, q2 = 0.f, q3 = 0.f;
    #pragma unroll 8
    for (int i = 0; i < 64; ++i) {
      const float r0 = urow[i], r1 = urow[i + 64], r2 = urow[i + 128], r3 = urow[i + 192];
      p0 = fmaf(r0, W1[(i      ) * HFF_ + t], p0);
      p1 = fmaf(r1, W1[(i +  64) * HFF_ + t], p1);
      p2 = fmaf(r2, W1[(i + 128) * HFF_ + t], p2);
      p3 = fmaf(r3, W1[(i + 192) * HFF_ + t], p3);
      q0 = fmaf(r0, W1[(i      ) * HFF_ + 256 + t], q0);
      q1 = fmaf(r1, W1[(i +  64) * HFF_ + 256 + t], q1);
      q2 = fmaf(r2, W1[(i + 128) * HFF_ + 256 + t], q2);
      q3 = fmaf(r3, W1[(i + 192) * HFF_ + 256 + t], q3);
    }
    pre_u[blk * HFF_ + t] = (_Float16)((p0 + p1) + (p2 + p3));
    pre_u[blk * HFF_ + 256 + t] = (_Float16)((q0 + q1) + (q2 + q3));
  } else if (blk < K_ + B_ * F_) {
    __shared__ float row2[D_];
    __shared__ float vrow[H_];
    const int bf = blk - K_;
    row2[t] = xhat[bf * D_ + t];
    __syncthreads();
    float a0 = 0.f, a1 = 0.f, a2 = 0.f, a3 = 0.f;
    #pragma unroll 8
    for (int i = 0; i < 64; ++i) {
      a0 = fmaf(row2[i      ], Wcat[(H_ + i      ) * H_ + t], a0);
      a1 = fmaf(row2[i +  64], Wcat[(H_ + i +  64) * H_ + t], a1);
      a2 = fmaf(row2[i + 128], Wcat[(H_ + i + 128) * H_ + t], a2);
      a3 = fmaf(row2[i + 192], Wcat[(H_ + i + 192) * H_ + t], a3);
    }
    const float vv = bcat[t] + ((a0 + a1) + (a2 + a3));
    v[bf * H_ + t] = vv;
    vrow[t] = vv;
    __syncthreads();
    // fused pre_v[bf] = vrow @ W1_0 + b1_0 (same chain as old k_prep2)
    float p0 = 0.f, p1 = 0.f, p2 = 0.f, p3 = 0.f;
    float q0 = 0.f, q1 = 0.f, q2 = 0.f, q3 = 0.f;
    #pragma unroll 8
    for (int i = 0; i < 64; ++i) {
      const float r0 = vrow[i], r1 = vrow[i + 64], r2 = vrow[i + 128], r3 = vrow[i + 192];
      p0 = fmaf(r0, W1[(i      ) * HFF_ + t], p0);
      p1 = fmaf(r1, W1[(i +  64) * HFF_ + t], p1);
      p2 = fmaf(r2, W1[(i + 128) * HFF_ + t], p2);
      p3 = fmaf(r3, W1[(i + 192) * HFF_ + t], p3);
      q0 = fmaf(r0, W1[(i      ) * HFF_ + 256 + t], q0);
      q1 = fmaf(r1, W1[(i +  64) * HFF_ + 256 + t], q1);
      q2 = fmaf(r2, W1[(i + 128) * HFF_ + 256 + t], q2);
      q3 = fmaf(r3, W1[(i + 192) * HFF_ + 256 + t], q3);
    }
    pre_v[bf * HFF_ + t] = (_Float16)(((p0 + p1) + (p2 + p3)) + b1[t]);
    pre_v[bf * HFF_ + 256 + t] = (_Float16)(((q0 + q1) + (q2 + q3)) + b1[256 + t]);
  } else {
    const int e = (blk - (K_ + B_ * F_)) * 256 + t;
    const float* src; _Float16* dst; int N, NT, le;
    if (e < 262144) {
      const int layer = e >> 17; le = e & 131071;
      src = W1 + layer * (H_ * HFF_); dst = w1f + layer * (H_ * HFF_);
      N = HFF_; NT = 32;
    } else if (e < 524288) {
      const int e2 = e - 262144;
      const int layer = e2 >> 17; le = e2 & 131071;
      src = W2 + layer * (HFF_ * H_); dst = w2f + layer * (HFF_ * H_);
      N = H_; NT = 16;
    } else {
      le = e - 524288; src = Wout; dst = wof; N = D_; NT = 16;
    }
    const int jj = le & 7, lane = (le >> 3) & 63, r = le >> 9;
    const int ntile = r % NT, kstep = r / NT;
    const int row = kstep * 32 + (lane >> 4) * 8 + jj;
    const int colc = ntile * 16 + (lane & 15);
    dst[le] = (_Float16)src[row * N + colc];
  }
}

// ---------------------------------------------------------------------------
// MFMA main kernel (R18 verified body): layer-0 GEMM1 via pre-tables,
// hm staged through hmA; layers barrier-synced; 3 blocks/CU.
__global__ __launch_bounds__(256, 3) void k_main(
    const float* __restrict__ u, const float* __restrict__ v,
    const _Float16* __restrict__ w1f, const float* __restrict__ b1,
    const _Float16* __restrict__ w2f, const float* __restrict__ b2,
    const _Float16* __restrict__ woutf, const float* __restrict__ bout,
    const float* __restrict__ cb, const float* __restrict__ xhat,
    const float* __restrict__ x, const _Float16* __restrict__ pre_u,
    const _Float16* __restrict__ pre_v, float* __restrict__ dists) {
  __shared__ _Float16 hA[64][HA_S];    // 33280 B
  __shared__ _Float16 hmA[64][HMA_S];  // 16896 B
  __shared__ float x_s[D_], xh_s[D_];  // 2048 B
  __shared__ float dist_s[4][64];      // 1024 B

  const int t = threadIdx.x;
  const int blk = blockIdx.x;
  const int bf = blk >> 2, k0 = (blk & 3) << 6;
  const int b = bf >> 3, f = bf & 7;
  const int wave = t >> 6, lane = t & 63;
  const int col = lane & 15, quad = lane >> 4;
  const int lane8 = lane * 8;

  x_s[t]  = x[b * D_ + t];
  xh_s[t] = xhat[bf * D_ + t];

  // stage h = u + v -> fp16, packed 16B writes
  {
    const int r = t >> 2, c0 = (t & 3) * 64;
    const float* up = u + (k0 + r) * H_ + c0;
    const float* vp = v + bf * H_ + c0;
    #pragma unroll
    for (int j = 0; j < 64; j += 8) {
      float4 uA = *(const float4*)(up + j);
      float4 vA = *(const float4*)(vp + j);
      float4 uB = *(const float4*)(up + j + 4);
      float4 vB = *(const float4*)(vp + j + 4);
      half8 hv8;
      hv8[0] = (_Float16)(uA.x + vA.x); hv8[1] = (_Float16)(uA.y + vA.y);
      hv8[2] = (_Float16)(uA.z + vA.z); hv8[3] = (_Float16)(uA.w + vA.w);
      hv8[4] = (_Float16)(uB.x + vB.x); hv8[5] = (_Float16)(uB.y + vB.y);
      hv8[6] = (_Float16)(uB.z + vB.z); hv8[7] = (_Float16)(uB.w + vB.w);
      *(half8*)&hA[r][c0 + j] = hv8;
    }
  }
  __syncthreads();

  const floatx4 zero4 = {0.f, 0.f, 0.f, 0.f};

  #pragma unroll 1
  for (int l = 0; l < 2; ++l) {
    const _Float16* w1_l = w1f + l * (H_ * HFF_);
    const _Float16* w2_l = w2f + l * (HFF_ * H_);
    const float* b1l = b1 + l * HFF_;
    const float* b2l = b2 + l * H_;

    floatx4 acc2[4][4];   // [out-feature tile][candidate-row tile]
    #pragma unroll
    for (int mt = 0; mt < 4; ++mt)
      #pragma unroll
      for (int nt = 0; nt < 4; ++nt) acc2[mt][nt] = zero4;

    #pragma unroll 1
    for (int ch = 0; ch < 4; ++ch) {
      if (l == 0) {
        // ---- layer-0 GEMM1 eliminated: hm = relu(pre_u[k] + pre_v[bf]) ----
        const int r = t >> 2, c0 = (t & 3) * 32;
        const _Float16* pup = pre_u + (k0 + r) * HFF_ + ch * 128 + c0;
        const _Float16* pvp = pre_v + bf * HFF_ + ch * 128 + c0;
        #pragma unroll
        for (int j = 0; j < 32; j += 8) {
          half8 pu = *(const half8*)(pup + j);
          half8 pv = *(const half8*)(pvp + j);
          half8 hm;
          #pragma unroll
          for (int p = 0; p < 8; ++p) {
            const _Float16 s = pu[p] + pv[p];
            hm[p] = s > (_Float16)0.f ? s : (_Float16)0.f;
          }
          *(half8*)&hmA[r][c0 + j] = hm;
        }
      } else {
        // ---- GEMM1': hm' = relu(W1[:,chunk]^T @ h^T + b1) ----
        floatx4 acc1[2][4];
        #pragma unroll
        for (int mt = 0; mt < 2; ++mt)
          #pragma unroll
          for (int nt = 0; nt < 4; ++nt) acc1[mt][nt] = zero4;

        const _Float16* w1_b = w1_l + (ch * 8 + wave * 2) * 512 + lane8;

        __builtin_amdgcn_s_setprio(1);
        #pragma unroll 4
        for (int ks = 0; ks < 8; ++ks) {
          half8 b0 = *(const half8*)&hA[col][ks * 32 + quad * 8];
          half8 b1v = *(const half8*)&hA[16 + col][ks * 32 + quad * 8];
          half8 b2v = *(const half8*)&hA[32 + col][ks * 32 + quad * 8];
          half8 b3v = *(const half8*)&hA[48 + col][ks * 32 + quad * 8];
          const int ko = ks * 32 * 512;
          #pragma unroll
          for (int mt = 0; mt < 2; ++mt) {
            half8 aw = *(const half8*)(w1_b + ko + mt * 512);
            acc1[mt][0] = MFMAH(aw, b0, acc1[mt][0]);
            acc1[mt][1] = MFMAH(aw, b1v, acc1[mt][1]);
            acc1[mt][2] = MFMAH(aw, b2v, acc1[mt][2]);
            acc1[mt][3] = MFMAH(aw, b3v, acc1[mt][3]);
          }
        }
        __builtin_amdgcn_s_setprio(0);
        // bias + relu -> fp16, packed 8B stores
        #pragma unroll
        for (int mt = 0; mt < 2; ++mt) {
          const int floc = (wave * 2 + mt) * 16 + quad * 4;
          float4 bb = *(const float4*)&b1l[ch * 128 + floc];
          #pragma unroll
          for (int nt = 0; nt < 4; ++nt) {
            const int row = nt * 16 + col;
            half4v nh;
            #pragma unroll
            for (int p = 0; p < 4; ++p)
              nh[p] = (_Float16)fmaxf(acc1[mt][nt][p] + ((const float*)&bb)[p], 0.f);
            *(half4v*)&hmA[row][floc] = nh;
          }
        }
      }
      __syncthreads();

      // ---- GEMM2': acc2 += W2[chunk,:]^T @ hm'^T ----
      const _Float16* w2_b = w2_l + (ch * 64 + wave * 4) * 512 + lane8;
      __builtin_amdgcn_s_setprio(1);
      #pragma unroll 2
      for (int ks = 0; ks < 4; ++ks) {
        half8 b0 = *(const half8*)&hmA[col][ks * 32 + quad * 8];
        half8 b1v = *(const half8*)&hmA[16 + col][ks * 32 + quad * 8];
        half8 b2v = *(const half8*)&hmA[32 + col][ks * 32 + quad * 8];
        half8 b3v = *(const half8*)&hmA[48 + col][ks * 32 + quad * 8];
        const int ko = ks * 16 * 512;
        #pragma unroll
        for (int mt = 0; mt < 4; ++mt) {
          half8 aw = *(const half8*)(w2_b + ko + mt * 512);
          acc2[mt][0] = MFMAH(aw, b0, acc2[mt][0]);
          acc2[mt][1] = MFMAH(aw, b1v, acc2[mt][1]);
          acc2[mt][2] = MFMAH(aw, b2v, acc2[mt][2]);
          acc2[mt][3] = MFMAH(aw, b3v, acc2[mt][3]);
        }
      }
      __builtin_amdgcn_s_setprio(0);
      __syncthreads();
    }

    // ---- residual: h += acc2 + b2, packed 8B read/modify/write ----
    #pragma unroll
    for (int mt = 0; mt < 4; ++mt) {
      const int feat0 = (wave * 4 + mt) * 16 + quad * 4;
      float4 bb = *(const float4*)&b2l[feat0];
      #pragma unroll
      for (int nt = 0; nt < 4; ++nt) {
        const int row = nt * 16 + col;
        half4v oh = *(half4v*)&hA[row][feat0];
        half4v nh;
        #pragma unroll
        for (int p = 0; p < 4; ++p)
          nh[p] = (_Float16)((float)oh[p] + acc2[mt][nt][p] + ((const float*)&bb)[p]);
        *(half4v*)&hA[row][feat0] = nh;
      }
    }
    __syncthreads();
  }

  // ---- GEMM3': cw' = Wout^T @ h^T (+bout+cb+xhat), then distance ----
  floatx4 acc3[4][4];
  #pragma unroll
  for (int mt = 0; mt < 4; ++mt)
    #pragma unroll
    for (int nt = 0; nt < 4; ++nt) acc3[mt][nt] = zero4;

  const _Float16* wo_b = woutf + (wave * 4) * 512 + lane8;
  __builtin_amdgcn_s_setprio(1);
  #pragma unroll 2
  for (int ks = 0; ks < 8; ++ks) {
    half8 b0 = *(const half8*)&hA[col][ks * 32 + quad * 8];
    half8 b1v = *(const half8*)&hA[16 + col][ks * 32 + quad * 8];
    half8 b2v = *(const half8*)&hA[32 + col][ks * 32 + quad * 8];
    half8 b3v = *(const half8*)&hA[48 + col][ks * 32 + quad * 8];
    const int ko = ks * 16 * 512;
    #pragma unroll
    for (int mt = 0; mt < 4; ++mt) {
      half8 aw = *(const half8*)(wo_b + ko + mt * 512);
      acc3[mt][0] = MFMAH(aw, b0, acc3[mt][0]);
      acc3[mt][1] = MFMAH(aw, b1v, acc3[mt][1]);
      acc3[mt][2] = MFMAH(aw, b2v, acc3[mt][2]);
      acc3[mt][3] = MFMAH(aw, b3v, acc3[mt][3]);
    }
  }
  __builtin_amdgcn_s_setprio(0);

  float s[4] = {0.f, 0.f, 0.f, 0.f};
  #pragma unroll
  for (int mt = 0; mt < 4; ++mt) {
    const int d0 = (wave * 4 + mt) * 16 + quad * 4;
    float4 bo = *(const float4*)&bout[d0];
    float4 xv = *(const float4*)&x_s[d0];
    float4 xh4 = *(const float4*)&xh_s[d0];
    #pragma unroll
    for (int nt = 0; nt < 4; ++nt) {
      float4 cbv = *(const float4*)&cb[(k0 + nt * 16 + col) * D_ + d0];
      #pragma unroll
      for (int p = 0; p < 4; ++p) {
        float base = ((const float*)&bo)[p] + ((const float*)&xh4)[p];
        float xx = ((const float*)&xv)[p];
        float cw = acc3[mt][nt][p] + base + ((const float*)&cbv)[p];
        s[nt] += cw * (cw - 2.f * xx);   // -||x||^2 const: argmin-invariant
      }
    }
  }
  #pragma unroll
  for (int nt = 0; nt < 4; ++nt) {
    s[nt] += __shfl_xor(s[nt], 16, 64);
    s[nt] += __shfl_xor(s[nt], 32, 64);
  }
  if (quad == 0) {
    #pragma unroll
    for (int nt = 0; nt < 4; ++nt)
      dist_s[wave][nt * 16 + col] = s[nt];
  }
  __syncthreads();
  if (t < 64) {
    float d = dist_s[0][t] + dist_s[1][t] + dist_s[2][t] + dist_s[3][t];
    dists[b * (F_ * K_) + f * K_ + k0 + t] = d;
  }
}

// ---------------------------------------------------------------------------
// top-8: wave-level shfl_xor (val,idx) butterfly — 2 barriers/pass.
__global__ void k_top8(const float* __restrict__ dists, int* __restrict__ topi) {
  __shared__ float ds[F_ * K_];
  __shared__ float wv[8];
  __shared__ int   wi[8];
  const int b = blockIdx.x, t = threadIdx.x;
  const int wave = t >> 6, lane = t & 63;
  for (int j = t; j < F_ * K_; j += 512) ds[j] = dists[b * (F_ * K_) + j];
  __syncthreads();
  for (int pass = 0; pass < 8; ++pass) {
    float best = 3.4e38f; int bi = 0;
    #pragma unroll
    for (int j = t; j < F_ * K_; j += 512) {
      const float dv = ds[j];
      if (dv < best) { best = dv; bi = j; }
    }
    #pragma unroll
    for (int off = 1; off < 64; off <<= 1) {
      const float ov = __shfl_xor(best, off, 64);
      const int oi = __shfl_xor(bi, off, 64);
      if (ov < best || (ov == best && oi < bi)) { best = ov; bi = oi; }
    }
    if (lane == 0) { wv[wave] = best; wi[wave] = bi; }
    __syncthreads();
    if (t == 0) {
      float bv2 = wv[0]; int bi2 = wi[0];
      #pragma unroll
      for (int w = 1; w < 8; ++w)
        if (wv[w] < bv2 || (wv[w] == bv2 && wi[w] < bi2)) { bv2 = wv[w]; bi2 = wi[w]; }
      topi[b * 8 + pass] = bi2;
      ds[bi2] = 3.4e38f;
    }
    __syncthreads();
  }
}

// ---------------------------------------------------------------------------
// Exact rescore, 256 blocks x 512 threads (R15/R22 verified; R25: unroll 8).
#define NCL 2
__global__ __launch_bounds__(512) void k_resfin(
    const float* __restrict__ u, const float* __restrict__ v,
    const float* __restrict__ W1, const float* __restrict__ b1,
    const float* __restrict__ W2, const float* __restrict__ b2,
    const float* __restrict__ Wout, const float* __restrict__ bout,
    const float* __restrict__ cb, const float* __restrict__ xhat,
    const float* __restrict__ x, const int* __restrict__ topi,
    float* __restrict__ resc2, int* __restrict__ iwin2,
    float* __restrict__ cwhalf) {
  __shared__ float hs4[4][H_ + 4];      // 4160 B (rows 16B-aligned)
  __shared__ float hms4[4][HFF_ + 4];   // 8256 B
  __shared__ float cw4[4][H_ + 4];      // 4160 B
  __shared__ float redw[8][NCL];
  __shared__ int   sel_sh;

  const int blk = blockIdx.x;
  const int b = blk >> 1, half = blk & 1;
  const int t = threadIdx.x;
  const int g = t >> 8, tloc = t & 255;
  const int wave = t >> 6, lane = t & 63;
  const int cbase = half * 4;

  int kc[NCL], bfc[NCL];
  #pragma unroll
  for (int cl = 0; cl < NCL; ++cl) {
    const int ix = topi[b * 8 + cbase + g * 2 + cl];
    kc[cl] = ix & 255;
    bfc[cl] = b * F_ + (ix >> 8);
  }

  #pragma unroll
  for (int cl = 0; cl < NCL; ++cl)
    hs4[g * 2 + cl][tloc] = u[kc[cl] * H_ + tloc] + v[bfc[cl] * H_ + tloc];
  __syncthreads();

  #pragma unroll 1
  for (int l = 0; l < 2; ++l) {
    const float* W1l = W1 + l * (H_ * HFF_);
    const float* W2l = W2 + l * (HFF_ * H_);

    float a0[NCL], a1[NCL];
    {
      const float bb0 = b1[l * HFF_ + tloc], bb1 = b1[l * HFF_ + 256 + tloc];
      #pragma unroll
      for (int cl = 0; cl < NCL; ++cl) { a0[cl] = bb0; a1[cl] = bb1; }
    }
    #pragma unroll 8
    for (int i = 0; i < H_; i += 4) {
      float4 hv[NCL];
      #pragma unroll
      for (int cl = 0; cl < NCL; ++cl) hv[cl] = *(const float4*)&hs4[g * 2 + cl][i];
      #pragma unroll
      for (int q = 0; q < 4; ++q) {
        const float w0 = W1l[(i + q) * HFF_ + tloc];
        const float w1 = W1l[(i + q) * HFF_ + 256 + tloc];
        #pragma unroll
        for (int cl = 0; cl < NCL; ++cl) {
          const float h = ((const float*)&hv[cl])[q];
          a0[cl] = fmaf(h, w0, a0[cl]);
          a1[cl] = fmaf(h, w1, a1[cl]);
        }
      }
    }
    #pragma unroll
    for (int cl = 0; cl < NCL; ++cl) {
      hms4[g * 2 + cl][tloc] = fmaxf(a0[cl], 0.f);
      hms4[g * 2 + cl][tloc + 256] = fmaxf(a1[cl], 0.f);
    }
    __syncthreads();

    float hn[NCL];
    {
      const float bb2 = b2[l * H_ + tloc];
      #pragma unroll
      for (int cl = 0; cl < NCL; ++cl) hn[cl] = hs4[g * 2 + cl][tloc] + bb2;
    }
    #pragma unroll 8
    for (int jj = 0; jj < HFF_; jj += 4) {
      float4 hv[NCL];
      #pragma unroll
      for (int cl = 0; cl < NCL; ++cl) hv[cl] = *(const float4*)&hms4[g * 2 + cl][jj];
      #pragma unroll
      for (int q = 0; q < 4; ++q) {
        const float w = W2l[(jj + q) * H_ + tloc];
        #pragma unroll
        for (int cl = 0; cl < NCL; ++cl)
          hn[cl] = fmaf(((const float*)&hv[cl])[q], w, hn[cl]);
      }
    }
    __syncthreads();
    #pragma unroll
    for (int cl = 0; cl < NCL; ++cl) hs4[g * 2 + cl][tloc] = hn[cl];
    __syncthreads();
  }

  float cw[NCL];
  {
    const float bo = bout[tloc];
    #pragma unroll
    for (int cl = 0; cl < NCL; ++cl)
      cw[cl] = bo + cb[kc[cl] * D_ + tloc] + xhat[bfc[cl] * D_ + tloc];
  }
  #pragma unroll 8
  for (int i = 0; i < H_; i += 4) {
    float4 hv[NCL];
    #pragma unroll
    for (int cl = 0; cl < NCL; ++cl) hv[cl] = *(const float4*)&hs4[g * 2 + cl][i];
    #pragma unroll
    for (int q = 0; q < 4; ++q) {
      const float w = Wout[(i + q) * D_ + tloc];
      #pragma unroll
      for (int cl = 0; cl < NCL; ++cl)
        cw[cl] = fmaf(((const float*)&hv[cl])[q], w, cw[cl]);
    }
  }

  const float xx = x[b * D_ + tloc];
  #pragma unroll
  for (int cl = 0; cl < NCL; ++cl) {
    cw4[g * 2 + cl][tloc] = cw[cl];
    float vsum = cw[cl] * (cw[cl] - 2.f * xx);
    vsum += __shfl_xor(vsum, 1, 64);
    vsum += __shfl_xor(vsum, 2, 64);
    vsum += __shfl_xor(vsum, 4, 64);
    vsum += __shfl_xor(vsum, 8, 64);
    vsum += __shfl_xor(vsum, 16, 64);
    vsum += __shfl_xor(vsum, 32, 64);
    if (lane == 0) redw[wave][cl] = vsum;
  }
  __syncthreads();
  if (t == 0) {
    float bd = 3.4e38f; int bidx = 1 << 30; int bc = 0;
    #pragma unroll
    for (int c = 0; c < 4; ++c) {
      const int gg = c >> 1, cl = c & 1;
      const float d = redw[gg * 4 + 0][cl] + redw[gg * 4 + 1][cl] +
                      redw[gg * 4 + 2][cl] + redw[gg * 4 + 3][cl];
      const int ix = topi[b * 8 + cbase + c];
      if (d < bd || (d == bd && ix < bidx)) { bd = d; bidx = ix; bc = c; }
    }
    resc2[blk] = bd;
    iwin2[blk] = bidx;
    sel_sh = bc;
  }
  __syncthreads();
  if (t < 256) cwhalf[blk * 256 + t] = cw4[sel_sh][t];
}

// ---------------------------------------------------------------------------
// Combine the two halves' winners; write output.
__global__ void k_finw(const float* __restrict__ resc2, const int* __restrict__ iwin2,
                       const float* __restrict__ cwhalf, const int* __restrict__ codes,
                       float* __restrict__ out) {
  const int b = blockIdx.x, t = threadIdx.x;
  const float d0 = resc2[b * 2], d1 = resc2[b * 2 + 1];
  const int i0 = iwin2[b * 2], i1 = iwin2[b * 2 + 1];
  const int sel = (d1 < d0 || (d1 == d0 && i1 < i0)) ? 1 : 0;
  out[b * D_ + t] = cwhalf[(b * 2 + sel) * 256 + t];
  if (t < 2)
    out[B_ * D_ + t * B_ + b] = (float)codes[t * B_ + b];
  else if (t == 2)
    out[B_ * D_ + 2 * B_ + b] = (float)(sel ? i1 : i0);
}

// ---------------------------------------------------------------------------
extern "C" void kernel_launch(void* const* d_in, const int* in_sizes, int n_in,
                              void* d_out, int out_size, void* d_ws, size_t ws_size,
                              hipStream_t stream) {
  const float* x    = (const float*)d_in[0];
  const float* xhat = (const float*)d_in[1];
  const int*   codes= (const int*)d_in[2];
  const float* cb   = (const float*)d_in[3];
  const float* Win  = (const float*)d_in[4];
  const float* bin  = (const float*)d_in[5];
  const float* Wcat = (const float*)d_in[6];
  const float* bcat = (const float*)d_in[7];
  const float* W1   = (const float*)d_in[8];
  const float* b1   = (const float*)d_in[9];
  const float* W2   = (const float*)d_in[10];
  const float* b2   = (const float*)d_in[11];
  const float* Wout = (const float*)d_in[12];
  const float* bout = (const float*)d_in[13];
  float* out = (float*)d_out;

  float* u     = (float*)d_ws;                  // 65536 f (h0 eliminated)
  float* v     = u + K_ * H_;                   // 262144 f
  float* dists = v + B_ * F_ * H_;              // 262144 f
  float* resc  = dists + B_ * F_ * K_;          // 1024 f
  int*   topi  = (int*)(resc + 1024);           // 1024 i
  int*   pad   = topi + 1024;                   // 128 pad (keeps 16B align)
  _Float16* w1f  = (_Float16*)(pad + 128);      // 2*H*HFF halves
  _Float16* w2f  = w1f + 2 * H_ * HFF_;
  _Float16* wof  = w2f + 2 * HFF_ * H_;
  _Float16* pre_u = wof + H_ * D_;              // 256*512 halves
  _Float16* pre_v = pre_u + K_ * HFF_;          // 1024*512 halves

  float* resc2  = resc;
  int*   iwin2  = (int*)(resc + 256);
  float* cwhalf = dists;

  k_prep<<<K_ + B_ * F_ + 2304, 256, 0, stream>>>(cb, Win, bin, Wcat, bcat, xhat,
                                                  W1, b1, W2, Wout, u, v,
                                                  w1f, w2f, wof, pre_u, pre_v);

  k_main<<<B_ * F_ * (K_ / RT), 256, 0, stream>>>(u, v, w1f, b1, w2f, b2,
                                                  wof, bout, cb, xhat, x,
                                                  pre_u, pre_v, dists);
  k_top8<<<B_, 512, 0, stream>>>(dists, topi);
  k_resfin<<<2 * B_, 512, 0, stream>>>(u, v, W1, b1, W2, b2, Wout, bout, cb, xhat,
                                       x, topi, resc2, iwin2, cwhalf);
  k_finw<<<B_, 256, 0, stream>>>(resc2, iwin2, cwhalf, codes, out);
}

// Round 17
// 484.873 us; speedup vs baseline: 1.0238x; 1.0238x over previous
//
#include <hip/hip_runtime.h>
#include <hip/hip_bf16.h>

// Shapes (fixed): B=128, F=8, K=256, D=256, H=256, HFF=512, L=2, M_PREV=2
#define B_   128
#define F_   8
#define K_   256
#define D_   256
#define H_   256
#define HFF_ 512
#define RT   64   // candidates per block

typedef _Float16 half8  __attribute__((ext_vector_type(8)));  // f16x8 MFMA frag
typedef _Float16 half4v __attribute__((ext_vector_type(4)));
typedef float floatx4   __attribute__((ext_vector_type(4)));  // MFMA acc

#define MFMAH(a,b,c) __builtin_amdgcn_mfma_f32_16x16x32_f16(a,b,c,0,0,0)

// R26 = R24 verbatim (best verified: 485.5us total; R25's unroll-8 sides
// regressed to 496.4 -> sides confirmed at their issue-bound floor).
// Final session config: 567.5 -> 485.5us (-14.4%).
//   k_main 336us: R9 MFMA structure (3 blk/CU, verified local optimum) +
//     R18 algebraic layer-0 GEMM1 elimination via pre_u/pre_v tables.
//   sides ~150us: R15 k_resfin TLP split (256 blk x 512 thr) + R16 k_prep
//     4-acc ILP + R21 prep2 fusion + R22 unroll-4 / shfl-xor top8.
#define HA_S  260
#define HMA_S 132

// ---------------------------------------------------------------------------
// Fused prep — (h0->u->pre_u), (v->pre_v), and the fp16 weight shuffle.
__global__ void k_prep(const float* __restrict__ cb, const float* __restrict__ Win,
                       const float* __restrict__ bin, const float* __restrict__ Wcat,
                       const float* __restrict__ bcat, const float* __restrict__ xhat,
                       const float* __restrict__ W1, const float* __restrict__ b1,
                       const float* __restrict__ W2, const float* __restrict__ Wout,
                       float* __restrict__ u, float* __restrict__ v,
                       _Float16* __restrict__ w1f, _Float16* __restrict__ w2f,
                       _Float16* __restrict__ wof,
                       _Float16* __restrict__ pre_u, _Float16* __restrict__ pre_v) {
  const int blk = blockIdx.x, t = threadIdx.x;
  if (blk < K_) {
    __shared__ float row[D_];
    __shared__ float h0row[H_];
    __shared__ float urow[H_];
    row[t] = cb[blk * D_ + t];
    __syncthreads();
    float a0 = 0.f, a1 = 0.f, a2 = 0.f, a3 = 0.f;
    #pragma unroll 4
    for (int i = 0; i < 64; ++i) {
      a0 = fmaf(row[i      ], Win[(i      ) * H_ + t], a0);
      a1 = fmaf(row[i +  64], Win[(i +  64) * H_ + t], a1);
      a2 = fmaf(row[i + 128], Win[(i + 128) * H_ + t], a2);
      a3 = fmaf(row[i + 192], Win[(i + 192) * H_ + t], a3);
    }
    h0row[t] = bin[t] + ((a0 + a1) + (a2 + a3));
    __syncthreads();
    float c0 = 0.f, c1 = 0.f, c2 = 0.f, c3 = 0.f;
    #pragma unroll 4
    for (int i = 0; i < 64; ++i) {
      c0 = fmaf(h0row[i      ], Wcat[(i      ) * H_ + t], c0);
      c1 = fmaf(h0row[i +  64], Wcat[(i +  64) * H_ + t], c1);
      c2 = fmaf(h0row[i + 128], Wcat[(i + 128) * H_ + t], c2);
      c3 = fmaf(h0row[i + 192], Wcat[(i + 192) * H_ + t], c3);
    }
    const float uv = (c0 + c1) + (c2 + c3);
    u[blk * H_ + t] = uv;
    urow[t] = uv;
    __syncthreads();
    // fused pre_u[blk] = urow @ W1_0 (same 8-acc chain as old k_prep2)
    float p0 = 0.f, p1 = 0.f, p2 = 0.f, p3 = 0.f;
    float q0 = 0.f, q1 = 0.f, q2 = 0.f, q3 = 0.f;
    #pragma unroll 4
    for (int i = 0; i < 64; ++i) {
      const float r0 = urow[i], r1 = urow[i + 64], r2 = urow[i + 128], r3 = urow[i + 192];
      p0 = fmaf(r0, W1[(i      ) * HFF_ + t], p0);
      p1 = fmaf(r1, W1[(i +  64) * HFF_ + t], p1);
      p2 = fmaf(r2, W1[(i + 128) * HFF_ + t], p2);
      p3 = fmaf(r3, W1[(i + 192) * HFF_ + t], p3);
      q0 = fmaf(r0, W1[(i      ) * HFF_ + 256 + t], q0);
      q1 = fmaf(r1, W1[(i +  64) * HFF_ + 256 + t], q1);
      q2 = fmaf(r2, W1[(i + 128) * HFF_ + 256 + t], q2);
      q3 = fmaf(r3, W1[(i + 192) * HFF_ + 256 + t], q3);
    }
    pre_u[blk * HFF_ + t] = (_Float16)((p0 + p1) + (p2 + p3));
    pre_u[blk * HFF_ + 256 + t] = (_Float16)((q0 + q1) + (q2 + q3));
  } else if (blk < K_ + B_ * F_) {
    __shared__ float row2[D_];
    __shared__ float vrow[H_];
    const int bf = blk - K_;
    row2[t] = xhat[bf * D_ + t];
    __syncthreads();
    float a0 = 0.f, a1 = 0.f, a2 = 0.f, a3 = 0.f;
    #pragma unroll 4
    for (int i = 0; i < 64; ++i) {
      a0 = fmaf(row2[i      ], Wcat[(H_ + i      ) * H_ + t], a0);
      a1 = fmaf(row2[i +  64], Wcat[(H_ + i +  64) * H_ + t], a1);
      a2 = fmaf(row2[i + 128], Wcat[(H_ + i + 128) * H_ + t], a2);
      a3 = fmaf(row2[i + 192], Wcat[(H_ + i + 192) * H_ + t], a3);
    }
    const float vv = bcat[t] + ((a0 + a1) + (a2 + a3));
    v[bf * H_ + t] = vv;
    vrow[t] = vv;
    __syncthreads();
    // fused pre_v[bf] = vrow @ W1_0 + b1_0 (same chain as old k_prep2)
    float p0 = 0.f, p1 = 0.f, p2 = 0.f, p3 = 0.f;
    float q0 = 0.f, q1 = 0.f, q2 = 0.f, q3 = 0.f;
    #pragma unroll 4
    for (int i = 0; i < 64; ++i) {
      const float r0 = vrow[i], r1 = vrow[i + 64], r2 = vrow[i + 128], r3 = vrow[i + 192];
      p0 = fmaf(r0, W1[(i      ) * HFF_ + t], p0);
      p1 = fmaf(r1, W1[(i +  64) * HFF_ + t], p1);
      p2 = fmaf(r2, W1[(i + 128) * HFF_ + t], p2);
      p3 = fmaf(r3, W1[(i + 192) * HFF_ + t], p3);
      q0 = fmaf(r0, W1[(i      ) * HFF_ + 256 + t], q0);
      q1 = fmaf(r1, W1[(i +  64) * HFF_ + 256 + t], q1);
      q2 = fmaf(r2, W1[(i + 128) * HFF_ + 256 + t], q2);
      q3 = fmaf(r3, W1[(i + 192) * HFF_ + 256 + t], q3);
    }
    pre_v[bf * HFF_ + t] = (_Float16)(((p0 + p1) + (p2 + p3)) + b1[t]);
    pre_v[bf * HFF_ + 256 + t] = (_Float16)(((q0 + q1) + (q2 + q3)) + b1[256 + t]);
  } else {
    const int e = (blk - (K_ + B_ * F_)) * 256 + t;
    const float* src; _Float16* dst; int N, NT, le;
    if (e < 262144) {
      const int layer = e >> 17; le = e & 131071;
      src = W1 + layer * (H_ * HFF_); dst = w1f + layer * (H_ * HFF_);
      N = HFF_; NT = 32;
    } else if (e < 524288) {
      const int e2 = e - 262144;
      const int layer = e2 >> 17; le = e2 & 131071;
      src = W2 + layer * (HFF_ * H_); dst = w2f + layer * (HFF_ * H_);
      N = H_; NT = 16;
    } else {
      le = e - 524288; src = Wout; dst = wof; N = D_; NT = 16;
    }
    const int jj = le & 7, lane = (le >> 3) & 63, r = le >> 9;
    const int ntile = r % NT, kstep = r / NT;
    const int row = kstep * 32 + (lane >> 4) * 8 + jj;
    const int colc = ntile * 16 + (lane & 15);
    dst[le] = (_Float16)src[row * N + colc];
  }
}

// ---------------------------------------------------------------------------
// MFMA main kernel (R18 verified body): layer-0 GEMM1 via pre-tables,
// hm staged through hmA; layers barrier-synced; 3 blocks/CU.
__global__ __launch_bounds__(256, 3) void k_main(
    const float* __restrict__ u, const float* __restrict__ v,
    const _Float16* __restrict__ w1f, const float* __restrict__ b1,
    const _Float16* __restrict__ w2f, const float* __restrict__ b2,
    const _Float16* __restrict__ woutf, const float* __restrict__ bout,
    const float* __restrict__ cb, const float* __restrict__ xhat,
    const float* __restrict__ x, const _Float16* __restrict__ pre_u,
    const _Float16* __restrict__ pre_v, float* __restrict__ dists) {
  __shared__ _Float16 hA[64][HA_S];    // 33280 B
  __shared__ _Float16 hmA[64][HMA_S];  // 16896 B
  __shared__ float x_s[D_], xh_s[D_];  // 2048 B
  __shared__ float dist_s[4][64];      // 1024 B

  const int t = threadIdx.x;
  const int blk = blockIdx.x;
  const int bf = blk >> 2, k0 = (blk & 3) << 6;
  const int b = bf >> 3, f = bf & 7;
  const int wave = t >> 6, lane = t & 63;
  const int col = lane & 15, quad = lane >> 4;
  const int lane8 = lane * 8;

  x_s[t]  = x[b * D_ + t];
  xh_s[t] = xhat[bf * D_ + t];

  // stage h = u + v -> fp16, packed 16B writes
  {
    const int r = t >> 2, c0 = (t & 3) * 64;
    const float* up = u + (k0 + r) * H_ + c0;
    const float* vp = v + bf * H_ + c0;
    #pragma unroll
    for (int j = 0; j < 64; j += 8) {
      float4 uA = *(const float4*)(up + j);
      float4 vA = *(const float4*)(vp + j);
      float4 uB = *(const float4*)(up + j + 4);
      float4 vB = *(const float4*)(vp + j + 4);
      half8 hv8;
      hv8[0] = (_Float16)(uA.x + vA.x); hv8[1] = (_Float16)(uA.y + vA.y);
      hv8[2] = (_Float16)(uA.z + vA.z); hv8[3] = (_Float16)(uA.w + vA.w);
      hv8[4] = (_Float16)(uB.x + vB.x); hv8[5] = (_Float16)(uB.y + vB.y);
      hv8[6] = (_Float16)(uB.z + vB.z); hv8[7] = (_Float16)(uB.w + vB.w);
      *(half8*)&hA[r][c0 + j] = hv8;
    }
  }
  __syncthreads();

  const floatx4 zero4 = {0.f, 0.f, 0.f, 0.f};

  #pragma unroll 1
  for (int l = 0; l < 2; ++l) {
    const _Float16* w1_l = w1f + l * (H_ * HFF_);
    const _Float16* w2_l = w2f + l * (HFF_ * H_);
    const float* b1l = b1 + l * HFF_;
    const float* b2l = b2 + l * H_;

    floatx4 acc2[4][4];   // [out-feature tile][candidate-row tile]
    #pragma unroll
    for (int mt = 0; mt < 4; ++mt)
      #pragma unroll
      for (int nt = 0; nt < 4; ++nt) acc2[mt][nt] = zero4;

    #pragma unroll 1
    for (int ch = 0; ch < 4; ++ch) {
      if (l == 0) {
        // ---- layer-0 GEMM1 eliminated: hm = relu(pre_u[k] + pre_v[bf]) ----
        const int r = t >> 2, c0 = (t & 3) * 32;
        const _Float16* pup = pre_u + (k0 + r) * HFF_ + ch * 128 + c0;
        const _Float16* pvp = pre_v + bf * HFF_ + ch * 128 + c0;
        #pragma unroll
        for (int j = 0; j < 32; j += 8) {
          half8 pu = *(const half8*)(pup + j);
          half8 pv = *(const half8*)(pvp + j);
          half8 hm;
          #pragma unroll
          for (int p = 0; p < 8; ++p) {
            const _Float16 s = pu[p] + pv[p];
            hm[p] = s > (_Float16)0.f ? s : (_Float16)0.f;
          }
          *(half8*)&hmA[r][c0 + j] = hm;
        }
      } else {
        // ---- GEMM1': hm' = relu(W1[:,chunk]^T @ h^T + b1) ----
        floatx4 acc1[2][4];
        #pragma unroll
        for (int mt = 0; mt < 2; ++mt)
          #pragma unroll
          for (int nt = 0; nt < 4; ++nt) acc1[mt][nt] = zero4;

        const _Float16* w1_b = w1_l + (ch * 8 + wave * 2) * 512 + lane8;

        __builtin_amdgcn_s_setprio(1);
        #pragma unroll 4
        for (int ks = 0; ks < 8; ++ks) {
          half8 b0 = *(const half8*)&hA[col][ks * 32 + quad * 8];
          half8 b1v = *(const half8*)&hA[16 + col][ks * 32 + quad * 8];
          half8 b2v = *(const half8*)&hA[32 + col][ks * 32 + quad * 8];
          half8 b3v = *(const half8*)&hA[48 + col][ks * 32 + quad * 8];
          const int ko = ks * 32 * 512;
          #pragma unroll
          for (int mt = 0; mt < 2; ++mt) {
            half8 aw = *(const half8*)(w1_b + ko + mt * 512);
            acc1[mt][0] = MFMAH(aw, b0, acc1[mt][0]);
            acc1[mt][1] = MFMAH(aw, b1v, acc1[mt][1]);
            acc1[mt][2] = MFMAH(aw, b2v, acc1[mt][2]);
            acc1[mt][3] = MFMAH(aw, b3v, acc1[mt][3]);
          }
        }
        __builtin_amdgcn_s_setprio(0);
        // bias + relu -> fp16, packed 8B stores
        #pragma unroll
        for (int mt = 0; mt < 2; ++mt) {
          const int floc = (wave * 2 + mt) * 16 + quad * 4;
          float4 bb = *(const float4*)&b1l[ch * 128 + floc];
          #pragma unroll
          for (int nt = 0; nt < 4; ++nt) {
            const int row = nt * 16 + col;
            half4v nh;
            #pragma unroll
            for (int p = 0; p < 4; ++p)
              nh[p] = (_Float16)fmaxf(acc1[mt][nt][p] + ((const float*)&bb)[p], 0.f);
            *(half4v*)&hmA[row][floc] = nh;
          }
        }
      }
      __syncthreads();

      // ---- GEMM2': acc2 += W2[chunk,:]^T @ hm'^T ----
      const _Float16* w2_b = w2_l + (ch * 64 + wave * 4) * 512 + lane8;
      __builtin_amdgcn_s_setprio(1);
      #pragma unroll 2
      for (int ks = 0; ks < 4; ++ks) {
        half8 b0 = *(const half8*)&hmA[col][ks * 32 + quad * 8];
        half8 b1v = *(const half8*)&hmA[16 + col][ks * 32 + quad * 8];
        half8 b2v = *(const half8*)&hmA[32 + col][ks * 32 + quad * 8];
        half8 b3v = *(const half8*)&hmA[48 + col][ks * 32 + quad * 8];
        const int ko = ks * 16 * 512;
        #pragma unroll
        for (int mt = 0; mt < 4; ++mt) {
          half8 aw = *(const half8*)(w2_b + ko + mt * 512);
          acc2[mt][0] = MFMAH(aw, b0, acc2[mt][0]);
          acc2[mt][1] = MFMAH(aw, b1v, acc2[mt][1]);
          acc2[mt][2] = MFMAH(aw, b2v, acc2[mt][2]);
          acc2[mt][3] = MFMAH(aw, b3v, acc2[mt][3]);
        }
      }
      __builtin_amdgcn_s_setprio(0);
      __syncthreads();
    }

    // ---- residual: h += acc2 + b2, packed 8B read/modify/write ----
    #pragma unroll
    for (int mt = 0; mt < 4; ++mt) {
      const int feat0 = (wave * 4 + mt) * 16 + quad * 4;
      float4 bb = *(const float4*)&b2l[feat0];
      #pragma unroll
      for (int nt = 0; nt < 4; ++nt) {
        const int row = nt * 16 + col;
        half4v oh = *(half4v*)&hA[row][feat0];
        half4v nh;
        #pragma unroll
        for (int p = 0; p < 4; ++p)
          nh[p] = (_Float16)((float)oh[p] + acc2[mt][nt][p] + ((const float*)&bb)[p]);
        *(half4v*)&hA[row][feat0] = nh;
      }
    }
    __syncthreads();
  }

  // ---- GEMM3': cw' = Wout^T @ h^T (+bout+cb+xhat), then distance ----
  floatx4 acc3[4][4];
  #pragma unroll
  for (int mt = 0; mt < 4; ++mt)
    #pragma unroll
    for (int nt = 0; nt < 4; ++nt) acc3[mt][nt] = zero4;

  const _Float16* wo_b = woutf + (wave * 4) * 512 + lane8;
  __builtin_amdgcn_s_setprio(1);
  #pragma unroll 2
  for (int ks = 0; ks < 8; ++ks) {
    half8 b0 = *(const half8*)&hA[col][ks * 32 + quad * 8];
    half8 b1v = *(const half8*)&hA[16 + col][ks * 32 + quad * 8];
    half8 b2v = *(const half8*)&hA[32 + col][ks * 32 + quad * 8];
    half8 b3v = *(const half8*)&hA[48 + col][ks * 32 + quad * 8];
    const int ko = ks * 16 * 512;
    #pragma unroll
    for (int mt = 0; mt < 4; ++mt) {
      half8 aw = *(const half8*)(wo_b + ko + mt * 512);
      acc3[mt][0] = MFMAH(aw, b0, acc3[mt][0]);
      acc3[mt][1] = MFMAH(aw, b1v, acc3[mt][1]);
      acc3[mt][2] = MFMAH(aw, b2v, acc3[mt][2]);
      acc3[mt][3] = MFMAH(aw, b3v, acc3[mt][3]);
    }
  }
  __builtin_amdgcn_s_setprio(0);

  float s[4] = {0.f, 0.f, 0.f, 0.f};
  #pragma unroll
  for (int mt = 0; mt < 4; ++mt) {
    const int d0 = (wave * 4 + mt) * 16 + quad * 4;
    float4 bo = *(const float4*)&bout[d0];
    float4 xv = *(const float4*)&x_s[d0];
    float4 xh4 = *(const float4*)&xh_s[d0];
    #pragma unroll
    for (int nt = 0; nt < 4; ++nt) {
      float4 cbv = *(const float4*)&cb[(k0 + nt * 16 + col) * D_ + d0];
      #pragma unroll
      for (int p = 0; p < 4; ++p) {
        float base = ((const float*)&bo)[p] + ((const float*)&xh4)[p];
        float xx = ((const float*)&xv)[p];
        float cw = acc3[mt][nt][p] + base + ((const float*)&cbv)[p];
        s[nt] += cw * (cw - 2.f * xx);   // -||x||^2 const: argmin-invariant
      }
    }
  }
  #pragma unroll
  for (int nt = 0; nt < 4; ++nt) {
    s[nt] += __shfl_xor(s[nt], 16, 64);
    s[nt] += __shfl_xor(s[nt], 32, 64);
  }
  if (quad == 0) {
    #pragma unroll
    for (int nt = 0; nt < 4; ++nt)
      dist_s[wave][nt * 16 + col] = s[nt];
  }
  __syncthreads();
  if (t < 64) {
    float d = dist_s[0][t] + dist_s[1][t] + dist_s[2][t] + dist_s[3][t];
    dists[b * (F_ * K_) + f * K_ + k0 + t] = d;
  }
}

// ---------------------------------------------------------------------------
// top-8: wave-level shfl_xor (val,idx) butterfly — 2 barriers/pass.
__global__ void k_top8(const float* __restrict__ dists, int* __restrict__ topi) {
  __shared__ float ds[F_ * K_];
  __shared__ float wv[8];
  __shared__ int   wi[8];
  const int b = blockIdx.x, t = threadIdx.x;
  const int wave = t >> 6, lane = t & 63;
  for (int j = t; j < F_ * K_; j += 512) ds[j] = dists[b * (F_ * K_) + j];
  __syncthreads();
  for (int pass = 0; pass < 8; ++pass) {
    float best = 3.4e38f; int bi = 0;
    #pragma unroll
    for (int j = t; j < F_ * K_; j += 512) {
      const float dv = ds[j];
      if (dv < best) { best = dv; bi = j; }
    }
    #pragma unroll
    for (int off = 1; off < 64; off <<= 1) {
      const float ov = __shfl_xor(best, off, 64);
      const int oi = __shfl_xor(bi, off, 64);
      if (ov < best || (ov == best && oi < bi)) { best = ov; bi = oi; }
    }
    if (lane == 0) { wv[wave] = best; wi[wave] = bi; }
    __syncthreads();
    if (t == 0) {
      float bv2 = wv[0]; int bi2 = wi[0];
      #pragma unroll
      for (int w = 1; w < 8; ++w)
        if (wv[w] < bv2 || (wv[w] == bv2 && wi[w] < bi2)) { bv2 = wv[w]; bi2 = wi[w]; }
      topi[b * 8 + pass] = bi2;
      ds[bi2] = 3.4e38f;
    }
    __syncthreads();
  }
}

// ---------------------------------------------------------------------------
// Exact rescore, 256 blocks x 512 threads (R15/R22 verified; unroll 4).
#define NCL 2
__global__ __launch_bounds__(512) void k_resfin(
    const float* __restrict__ u, const float* __restrict__ v,
    const float* __restrict__ W1, const float* __restrict__ b1,
    const float* __restrict__ W2, const float* __restrict__ b2,
    const float* __restrict__ Wout, const float* __restrict__ bout,
    const float* __restrict__ cb, const float* __restrict__ xhat,
    const float* __restrict__ x, const int* __restrict__ topi,
    float* __restrict__ resc2, int* __restrict__ iwin2,
    float* __restrict__ cwhalf) {
  __shared__ float hs4[4][H_ + 4];      // 4160 B (rows 16B-aligned)
  __shared__ float hms4[4][HFF_ + 4];   // 8256 B
  __shared__ float cw4[4][H_ + 4];      // 4160 B
  __shared__ float redw[8][NCL];
  __shared__ int   sel_sh;

  const int blk = blockIdx.x;
  const int b = blk >> 1, half = blk & 1;
  const int t = threadIdx.x;
  const int g = t >> 8, tloc = t & 255;
  const int wave = t >> 6, lane = t & 63;
  const int cbase = half * 4;

  int kc[NCL], bfc[NCL];
  #pragma unroll
  for (int cl = 0; cl < NCL; ++cl) {
    const int ix = topi[b * 8 + cbase + g * 2 + cl];
    kc[cl] = ix & 255;
    bfc[cl] = b * F_ + (ix >> 8);
  }

  #pragma unroll
  for (int cl = 0; cl < NCL; ++cl)
    hs4[g * 2 + cl][tloc] = u[kc[cl] * H_ + tloc] + v[bfc[cl] * H_ + tloc];
  __syncthreads();

  #pragma unroll 1
  for (int l = 0; l < 2; ++l) {
    const float* W1l = W1 + l * (H_ * HFF_);
    const float* W2l = W2 + l * (HFF_ * H_);

    float a0[NCL], a1[NCL];
    {
      const float bb0 = b1[l * HFF_ + tloc], bb1 = b1[l * HFF_ + 256 + tloc];
      #pragma unroll
      for (int cl = 0; cl < NCL; ++cl) { a0[cl] = bb0; a1[cl] = bb1; }
    }
    #pragma unroll 4
    for (int i = 0; i < H_; i += 4) {
      float4 hv[NCL];
      #pragma unroll
      for (int cl = 0; cl < NCL; ++cl) hv[cl] = *(const float4*)&hs4[g * 2 + cl][i];
      #pragma unroll
      for (int q = 0; q < 4; ++q) {
        const float w0 = W1l[(i + q) * HFF_ + tloc];
        const float w1 = W1l[(i + q) * HFF_ + 256 + tloc];
        #pragma unroll
        for (int cl = 0; cl < NCL; ++cl) {
          const float h = ((const float*)&hv[cl])[q];
          a0[cl] = fmaf(h, w0, a0[cl]);
          a1[cl] = fmaf(h, w1, a1[cl]);
        }
      }
    }
    #pragma unroll
    for (int cl = 0; cl < NCL; ++cl) {
      hms4[g * 2 + cl][tloc] = fmaxf(a0[cl], 0.f);
      hms4[g * 2 + cl][tloc + 256] = fmaxf(a1[cl], 0.f);
    }
    __syncthreads();

    float hn[NCL];
    {
      const float bb2 = b2[l * H_ + tloc];
      #pragma unroll
      for (int cl = 0; cl < NCL; ++cl) hn[cl] = hs4[g * 2 + cl][tloc] + bb2;
    }
    #pragma unroll 4
    for (int jj = 0; jj < HFF_; jj += 4) {
      float4 hv[NCL];
      #pragma unroll
      for (int cl = 0; cl < NCL; ++cl) hv[cl] = *(const float4*)&hms4[g * 2 + cl][jj];
      #pragma unroll
      for (int q = 0; q < 4; ++q) {
        const float w = W2l[(jj + q) * H_ + tloc];
        #pragma unroll
        for (int cl = 0; cl < NCL; ++cl)
          hn[cl] = fmaf(((const float*)&hv[cl])[q], w, hn[cl]);
      }
    }
    __syncthreads();
    #pragma unroll
    for (int cl = 0; cl < NCL; ++cl) hs4[g * 2 + cl][tloc] = hn[cl];
    __syncthreads();
  }

  float cw[NCL];
  {
    const float bo = bout[tloc];
    #pragma unroll
    for (int cl = 0; cl < NCL; ++cl)
      cw[cl] = bo + cb[kc[cl] * D_ + tloc] + xhat[bfc[cl] * D_ + tloc];
  }
  #pragma unroll 4
  for (int i = 0; i < H_; i += 4) {
    float4 hv[NCL];
    #pragma unroll
    for (int cl = 0; cl < NCL; ++cl) hv[cl] = *(const float4*)&hs4[g * 2 + cl][i];
    #pragma unroll
    for (int q = 0; q < 4; ++q) {
      const float w = Wout[(i + q) * D_ + tloc];
      #pragma unroll
      for (int cl = 0; cl < NCL; ++cl)
        cw[cl] = fmaf(((const float*)&hv[cl])[q], w, cw[cl]);
    }
  }

  const float xx = x[b * D_ + tloc];
  #pragma unroll
  for (int cl = 0; cl < NCL; ++cl) {
    cw4[g * 2 + cl][tloc] = cw[cl];
    float vsum = cw[cl] * (cw[cl] - 2.f * xx);
    vsum += __shfl_xor(vsum, 1, 64);
    vsum += __shfl_xor(vsum, 2, 64);
    vsum += __shfl_xor(vsum, 4, 64);
    vsum += __shfl_xor(vsum, 8, 64);
    vsum += __shfl_xor(vsum, 16, 64);
    vsum += __shfl_xor(vsum, 32, 64);
    if (lane == 0) redw[wave][cl] = vsum;
  }
  __syncthreads();
  if (t == 0) {
    float bd = 3.4e38f; int bidx = 1 << 30; int bc = 0;
    #pragma unroll
    for (int c = 0; c < 4; ++c) {
      const int gg = c >> 1, cl = c & 1;
      const float d = redw[gg * 4 + 0][cl] + redw[gg * 4 + 1][cl] +
                      redw[gg * 4 + 2][cl] + redw[gg * 4 + 3][cl];
      const int ix = topi[b * 8 + cbase + c];
      if (d < bd || (d == bd && ix < bidx)) { bd = d; bidx = ix; bc = c; }
    }
    resc2[blk] = bd;
    iwin2[blk] = bidx;
    sel_sh = bc;
  }
  __syncthreads();
  if (t < 256) cwhalf[blk * 256 + t] = cw4[sel_sh][t];
}

// ---------------------------------------------------------------------------
// Combine the two halves' winners; write output.
__global__ void k_finw(const float* __restrict__ resc2, const int* __restrict__ iwin2,
                       const float* __restrict__ cwhalf, const int* __restrict__ codes,
                       float* __restrict__ out) {
  const int b = blockIdx.x, t = threadIdx.x;
  const float d0 = resc2[b * 2], d1 = resc2[b * 2 + 1];
  const int i0 = iwin2[b * 2], i1 = iwin2[b * 2 + 1];
  const int sel = (d1 < d0 || (d1 == d0 && i1 < i0)) ? 1 : 0;
  out[b * D_ + t] = cwhalf[(b * 2 + sel) * 256 + t];
  if (t < 2)
    out[B_ * D_ + t * B_ + b] = (float)codes[t * B_ + b];
  else if (t == 2)
    out[B_ * D_ + 2 * B_ + b] = (float)(sel ? i1 : i0);
}

// ---------------------------------------------------------------------------
extern "C" void kernel_launch(void* const* d_in, const int* in_sizes, int n_in,
                              void* d_out, int out_size, void* d_ws, size_t ws_size,
                              hipStream_t stream) {
  const float* x    = (const float*)d_in[0];
  const float* xhat = (const float*)d_in[1];
  const int*   codes= (const int*)d_in[2];
  const float* cb   = (const float*)d_in[3];
  const float* Win  = (const float*)d_in[4];
  const float* bin  = (const float*)d_in[5];
  const float* Wcat = (const float*)d_in[6];
  const float* bcat = (const float*)d_in[7];
  const float* W1   = (const float*)d_in[8];
  const float* b1   = (const float*)d_in[9];
  const float* W2   = (const float*)d_in[10];
  const float* b2   = (const float*)d_in[11];
  const float* Wout = (const float*)d_in[12];
  const float* bout = (const float*)d_in[13];
  float* out = (float*)d_out;

  float* u     = (float*)d_ws;                  // 65536 f (h0 eliminated)
  float* v     = u + K_ * H_;                   // 262144 f
  float* dists = v + B_ * F_ * H_;              // 262144 f
  float* resc  = dists + B_ * F_ * K_;          // 1024 f
  int*   topi  = (int*)(resc + 1024);           // 1024 i
  int*   pad   = topi + 1024;                   // 128 pad (keeps 16B align)
  _Float16* w1f  = (_Float16*)(pad + 128);      // 2*H*HFF halves
  _Float16* w2f  = w1f + 2 * H_ * HFF_;
  _Float16* wof  = w2f + 2 * HFF_ * H_;
  _Float16* pre_u = wof + H_ * D_;              // 256*512 halves
  _Float16* pre_v = pre_u + K_ * HFF_;          // 1024*512 halves

  float* resc2  = resc;
  int*   iwin2  = (int*)(resc + 256);
  float* cwhalf = dists;

  k_prep<<<K_ + B_ * F_ + 2304, 256, 0, stream>>>(cb, Win, bin, Wcat, bcat, xhat,
                                                  W1, b1, W2, Wout, u, v,
                                                  w1f, w2f, wof, pre_u, pre_v);

  k_main<<<B_ * F_ * (K_ / RT), 256, 0, stream>>>(u, v, w1f, b1, w2f, b2,
                                                  wof, bout, cb, xhat, x,
                                                  pre_u, pre_v, dists);
  k_top8<<<B_, 512, 0, stream>>>(dists, topi);
  k_resfin<<<2 * B_, 512, 0, stream>>>(u, v, W1, b1, W2, b2, Wout, bout, cb, xhat,
                                       x, topi, resc2, iwin2, cwhalf);
  k_finw<<<B_, 256, 0, stream>>>(resc2, iwin2, cwhalf, codes, out);
}

// Round 18
// 483.492 us; speedup vs baseline: 1.0267x; 1.0029x over previous
//
#include <hip/hip_runtime.h>
#include <hip/hip_bf16.h>

// Shapes (fixed): B=128, F=8, K=256, D=256, H=256, HFF=512, L=2, M_PREV=2
#define B_   128
#define F_   8
#define K_   256
#define D_   256
#define H_   256
#define HFF_ 512
#define RT   64   // candidates per block

typedef _Float16 half8  __attribute__((ext_vector_type(8)));  // f16x8 MFMA frag
typedef _Float16 half4v __attribute__((ext_vector_type(4)));
typedef float floatx4   __attribute__((ext_vector_type(4)));  // MFMA acc

#define MFMAH(a,b,c) __builtin_amdgcn_mfma_f32_16x16x32_f16(a,b,c,0,0,0)

// FINAL (R27 = R24/R26, twice-verified 485us; session 567.5 -> 484.9, -14.6%).
//   k_main 335us: R9 MFMA structure (3 blk/CU implicit cross-block overlap;
//     5 restructures all regressed) + R18 algebraic layer-0 GEMM1
//     elimination (linearity of W1_0^T(u+v) -> pre_u/pre_v tables).
//   sides ~150us: R15 k_resfin TLP split (256 blk x 512 thr, 8x weight
//     reuse) + R16 k_prep 4-acc ILP + R21 prep2 fusion + R22 unroll-4 and
//     shfl-xor top8. NCL=4 / unroll-8 / merges all regressed -> at floor.
#define HA_S  260
#define HMA_S 132

// ---------------------------------------------------------------------------
// Fused prep — (h0->u->pre_u), (v->pre_v), and the fp16 weight shuffle.
__global__ void k_prep(const float* __restrict__ cb, const float* __restrict__ Win,
                       const float* __restrict__ bin, const float* __restrict__ Wcat,
                       const float* __restrict__ bcat, const float* __restrict__ xhat,
                       const float* __restrict__ W1, const float* __restrict__ b1,
                       const float* __restrict__ W2, const float* __restrict__ Wout,
                       float* __restrict__ u, float* __restrict__ v,
                       _Float16* __restrict__ w1f, _Float16* __restrict__ w2f,
                       _Float16* __restrict__ wof,
                       _Float16* __restrict__ pre_u, _Float16* __restrict__ pre_v) {
  const int blk = blockIdx.x, t = threadIdx.x;
  if (blk < K_) {
    __shared__ float row[D_];
    __shared__ float h0row[H_];
    __shared__ float urow[H_];
    row[t] = cb[blk * D_ + t];
    __syncthreads();
    float a0 = 0.f, a1 = 0.f, a2 = 0.f, a3 = 0.f;
    #pragma unroll 4
    for (int i = 0; i < 64; ++i) {
      a0 = fmaf(row[i      ], Win[(i      ) * H_ + t], a0);
      a1 = fmaf(row[i +  64], Win[(i +  64) * H_ + t], a1);
      a2 = fmaf(row[i + 128], Win[(i + 128) * H_ + t], a2);
      a3 = fmaf(row[i + 192], Win[(i + 192) * H_ + t], a3);
    }
    h0row[t] = bin[t] + ((a0 + a1) + (a2 + a3));
    __syncthreads();
    float c0 = 0.f, c1 = 0.f, c2 = 0.f, c3 = 0.f;
    #pragma unroll 4
    for (int i = 0; i < 64; ++i) {
      c0 = fmaf(h0row[i      ], Wcat[(i      ) * H_ + t], c0);
      c1 = fmaf(h0row[i +  64], Wcat[(i +  64) * H_ + t], c1);
      c2 = fmaf(h0row[i + 128], Wcat[(i + 128) * H_ + t], c2);
      c3 = fmaf(h0row[i + 192], Wcat[(i + 192) * H_ + t], c3);
    }
    const float uv = (c0 + c1) + (c2 + c3);
    u[blk * H_ + t] = uv;
    urow[t] = uv;
    __syncthreads();
    // fused pre_u[blk] = urow @ W1_0 (same 8-acc chain as old k_prep2)
    float p0 = 0.f, p1 = 0.f, p2 = 0.f, p3 = 0.f;
    float q0 = 0.f, q1 = 0.f, q2 = 0.f, q3 = 0.f;
    #pragma unroll 4
    for (int i = 0; i < 64; ++i) {
      const float r0 = urow[i], r1 = urow[i + 64], r2 = urow[i + 128], r3 = urow[i + 192];
      p0 = fmaf(r0, W1[(i      ) * HFF_ + t], p0);
      p1 = fmaf(r1, W1[(i +  64) * HFF_ + t], p1);
      p2 = fmaf(r2, W1[(i + 128) * HFF_ + t], p2);
      p3 = fmaf(r3, W1[(i + 192) * HFF_ + t], p3);
      q0 = fmaf(r0, W1[(i      ) * HFF_ + 256 + t], q0);
      q1 = fmaf(r1, W1[(i +  64) * HFF_ + 256 + t], q1);
      q2 = fmaf(r2, W1[(i + 128) * HFF_ + 256 + t], q2);
      q3 = fmaf(r3, W1[(i + 192) * HFF_ + 256 + t], q3);
    }
    pre_u[blk * HFF_ + t] = (_Float16)((p0 + p1) + (p2 + p3));
    pre_u[blk * HFF_ + 256 + t] = (_Float16)((q0 + q1) + (q2 + q3));
  } else if (blk < K_ + B_ * F_) {
    __shared__ float row2[D_];
    __shared__ float vrow[H_];
    const int bf = blk - K_;
    row2[t] = xhat[bf * D_ + t];
    __syncthreads();
    float a0 = 0.f, a1 = 0.f, a2 = 0.f, a3 = 0.f;
    #pragma unroll 4
    for (int i = 0; i < 64; ++i) {
      a0 = fmaf(row2[i      ], Wcat[(H_ + i      ) * H_ + t], a0);
      a1 = fmaf(row2[i +  64], Wcat[(H_ + i +  64) * H_ + t], a1);
      a2 = fmaf(row2[i + 128], Wcat[(H_ + i + 128) * H_ + t], a2);
      a3 = fmaf(row2[i + 192], Wcat[(H_ + i + 192) * H_ + t], a3);
    }
    const float vv = bcat[t] + ((a0 + a1) + (a2 + a3));
    v[bf * H_ + t] = vv;
    vrow[t] = vv;
    __syncthreads();
    // fused pre_v[bf] = vrow @ W1_0 + b1_0 (same chain as old k_prep2)
    float p0 = 0.f, p1 = 0.f, p2 = 0.f, p3 = 0.f;
    float q0 = 0.f, q1 = 0.f, q2 = 0.f, q3 = 0.f;
    #pragma unroll 4
    for (int i = 0; i < 64; ++i) {
      const float r0 = vrow[i], r1 = vrow[i + 64], r2 = vrow[i + 128], r3 = vrow[i + 192];
      p0 = fmaf(r0, W1[(i      ) * HFF_ + t], p0);
      p1 = fmaf(r1, W1[(i +  64) * HFF_ + t], p1);
      p2 = fmaf(r2, W1[(i + 128) * HFF_ + t], p2);
      p3 = fmaf(r3, W1[(i + 192) * HFF_ + t], p3);
      q0 = fmaf(r0, W1[(i      ) * HFF_ + 256 + t], q0);
      q1 = fmaf(r1, W1[(i +  64) * HFF_ + 256 + t], q1);
      q2 = fmaf(r2, W1[(i + 128) * HFF_ + 256 + t], q2);
      q3 = fmaf(r3, W1[(i + 192) * HFF_ + 256 + t], q3);
    }
    pre_v[bf * HFF_ + t] = (_Float16)(((p0 + p1) + (p2 + p3)) + b1[t]);
    pre_v[bf * HFF_ + 256 + t] = (_Float16)(((q0 + q1) + (q2 + q3)) + b1[256 + t]);
  } else {
    const int e = (blk - (K_ + B_ * F_)) * 256 + t;
    const float* src; _Float16* dst; int N, NT, le;
    if (e < 262144) {
      const int layer = e >> 17; le = e & 131071;
      src = W1 + layer * (H_ * HFF_); dst = w1f + layer * (H_ * HFF_);
      N = HFF_; NT = 32;
    } else if (e < 524288) {
      const int e2 = e - 262144;
      const int layer = e2 >> 17; le = e2 & 131071;
      src = W2 + layer * (HFF_ * H_); dst = w2f + layer * (HFF_ * H_);
      N = H_; NT = 16;
    } else {
      le = e - 524288; src = Wout; dst = wof; N = D_; NT = 16;
    }
    const int jj = le & 7, lane = (le >> 3) & 63, r = le >> 9;
    const int ntile = r % NT, kstep = r / NT;
    const int row = kstep * 32 + (lane >> 4) * 8 + jj;
    const int colc = ntile * 16 + (lane & 15);
    dst[le] = (_Float16)src[row * N + colc];
  }
}

// ---------------------------------------------------------------------------
// MFMA main kernel (R18 verified body): layer-0 GEMM1 via pre-tables,
// hm staged through hmA; layers barrier-synced; 3 blocks/CU.
__global__ __launch_bounds__(256, 3) void k_main(
    const float* __restrict__ u, const float* __restrict__ v,
    const _Float16* __restrict__ w1f, const float* __restrict__ b1,
    const _Float16* __restrict__ w2f, const float* __restrict__ b2,
    const _Float16* __restrict__ woutf, const float* __restrict__ bout,
    const float* __restrict__ cb, const float* __restrict__ xhat,
    const float* __restrict__ x, const _Float16* __restrict__ pre_u,
    const _Float16* __restrict__ pre_v, float* __restrict__ dists) {
  __shared__ _Float16 hA[64][HA_S];    // 33280 B
  __shared__ _Float16 hmA[64][HMA_S];  // 16896 B
  __shared__ float x_s[D_], xh_s[D_];  // 2048 B
  __shared__ float dist_s[4][64];      // 1024 B

  const int t = threadIdx.x;
  const int blk = blockIdx.x;
  const int bf = blk >> 2, k0 = (blk & 3) << 6;
  const int b = bf >> 3, f = bf & 7;
  const int wave = t >> 6, lane = t & 63;
  const int col = lane & 15, quad = lane >> 4;
  const int lane8 = lane * 8;

  x_s[t]  = x[b * D_ + t];
  xh_s[t] = xhat[bf * D_ + t];

  // stage h = u + v -> fp16, packed 16B writes
  {
    const int r = t >> 2, c0 = (t & 3) * 64;
    const float* up = u + (k0 + r) * H_ + c0;
    const float* vp = v + bf * H_ + c0;
    #pragma unroll
    for (int j = 0; j < 64; j += 8) {
      float4 uA = *(const float4*)(up + j);
      float4 vA = *(const float4*)(vp + j);
      float4 uB = *(const float4*)(up + j + 4);
      float4 vB = *(const float4*)(vp + j + 4);
      half8 hv8;
      hv8[0] = (_Float16)(uA.x + vA.x); hv8[1] = (_Float16)(uA.y + vA.y);
      hv8[2] = (_Float16)(uA.z + vA.z); hv8[3] = (_Float16)(uA.w + vA.w);
      hv8[4] = (_Float16)(uB.x + vB.x); hv8[5] = (_Float16)(uB.y + vB.y);
      hv8[6] = (_Float16)(uB.z + vB.z); hv8[7] = (_Float16)(uB.w + vB.w);
      *(half8*)&hA[r][c0 + j] = hv8;
    }
  }
  __syncthreads();

  const floatx4 zero4 = {0.f, 0.f, 0.f, 0.f};

  #pragma unroll 1
  for (int l = 0; l < 2; ++l) {
    const _Float16* w1_l = w1f + l * (H_ * HFF_);
    const _Float16* w2_l = w2f + l * (HFF_ * H_);
    const float* b1l = b1 + l * HFF_;
    const float* b2l = b2 + l * H_;

    floatx4 acc2[4][4];   // [out-feature tile][candidate-row tile]
    #pragma unroll
    for (int mt = 0; mt < 4; ++mt)
      #pragma unroll
      for (int nt = 0; nt < 4; ++nt) acc2[mt][nt] = zero4;

    #pragma unroll 1
    for (int ch = 0; ch < 4; ++ch) {
      if (l == 0) {
        // ---- layer-0 GEMM1 eliminated: hm = relu(pre_u[k] + pre_v[bf]) ----
        const int r = t >> 2, c0 = (t & 3) * 32;
        const _Float16* pup = pre_u + (k0 + r) * HFF_ + ch * 128 + c0;
        const _Float16* pvp = pre_v + bf * HFF_ + ch * 128 + c0;
        #pragma unroll
        for (int j = 0; j < 32; j += 8) {
          half8 pu = *(const half8*)(pup + j);
          half8 pv = *(const half8*)(pvp + j);
          half8 hm;
          #pragma unroll
          for (int p = 0; p < 8; ++p) {
            const _Float16 s = pu[p] + pv[p];
            hm[p] = s > (_Float16)0.f ? s : (_Float16)0.f;
          }
          *(half8*)&hmA[r][c0 + j] = hm;
        }
      } else {
        // ---- GEMM1': hm' = relu(W1[:,chunk]^T @ h^T + b1) ----
        floatx4 acc1[2][4];
        #pragma unroll
        for (int mt = 0; mt < 2; ++mt)
          #pragma unroll
          for (int nt = 0; nt < 4; ++nt) acc1[mt][nt] = zero4;

        const _Float16* w1_b = w1_l + (ch * 8 + wave * 2) * 512 + lane8;

        __builtin_amdgcn_s_setprio(1);
        #pragma unroll 4
        for (int ks = 0; ks < 8; ++ks) {
          half8 b0 = *(const half8*)&hA[col][ks * 32 + quad * 8];
          half8 b1v = *(const half8*)&hA[16 + col][ks * 32 + quad * 8];
          half8 b2v = *(const half8*)&hA[32 + col][ks * 32 + quad * 8];
          half8 b3v = *(const half8*)&hA[48 + col][ks * 32 + quad * 8];
          const int ko = ks * 32 * 512;
          #pragma unroll
          for (int mt = 0; mt < 2; ++mt) {
            half8 aw = *(const half8*)(w1_b + ko + mt * 512);
            acc1[mt][0] = MFMAH(aw, b0, acc1[mt][0]);
            acc1[mt][1] = MFMAH(aw, b1v, acc1[mt][1]);
            acc1[mt][2] = MFMAH(aw, b2v, acc1[mt][2]);
            acc1[mt][3] = MFMAH(aw, b3v, acc1[mt][3]);
          }
        }
        __builtin_amdgcn_s_setprio(0);
        // bias + relu -> fp16, packed 8B stores
        #pragma unroll
        for (int mt = 0; mt < 2; ++mt) {
          const int floc = (wave * 2 + mt) * 16 + quad * 4;
          float4 bb = *(const float4*)&b1l[ch * 128 + floc];
          #pragma unroll
          for (int nt = 0; nt < 4; ++nt) {
            const int row = nt * 16 + col;
            half4v nh;
            #pragma unroll
            for (int p = 0; p < 4; ++p)
              nh[p] = (_Float16)fmaxf(acc1[mt][nt][p] + ((const float*)&bb)[p], 0.f);
            *(half4v*)&hmA[row][floc] = nh;
          }
        }
      }
      __syncthreads();

      // ---- GEMM2': acc2 += W2[chunk,:]^T @ hm'^T ----
      const _Float16* w2_b = w2_l + (ch * 64 + wave * 4) * 512 + lane8;
      __builtin_amdgcn_s_setprio(1);
      #pragma unroll 2
      for (int ks = 0; ks < 4; ++ks) {
        half8 b0 = *(const half8*)&hmA[col][ks * 32 + quad * 8];
        half8 b1v = *(const half8*)&hmA[16 + col][ks * 32 + quad * 8];
        half8 b2v = *(const half8*)&hmA[32 + col][ks * 32 + quad * 8];
        half8 b3v = *(const half8*)&hmA[48 + col][ks * 32 + quad * 8];
        const int ko = ks * 16 * 512;
        #pragma unroll
        for (int mt = 0; mt < 4; ++mt) {
          half8 aw = *(const half8*)(w2_b + ko + mt * 512);
          acc2[mt][0] = MFMAH(aw, b0, acc2[mt][0]);
          acc2[mt][1] = MFMAH(aw, b1v, acc2[mt][1]);
          acc2[mt][2] = MFMAH(aw, b2v, acc2[mt][2]);
          acc2[mt][3] = MFMAH(aw, b3v, acc2[mt][3]);
        }
      }
      __builtin_amdgcn_s_setprio(0);
      __syncthreads();
    }

    // ---- residual: h += acc2 + b2, packed 8B read/modify/write ----
    #pragma unroll
    for (int mt = 0; mt < 4; ++mt) {
      const int feat0 = (wave * 4 + mt) * 16 + quad * 4;
      float4 bb = *(const float4*)&b2l[feat0];
      #pragma unroll
      for (int nt = 0; nt < 4; ++nt) {
        const int row = nt * 16 + col;
        half4v oh = *(half4v*)&hA[row][feat0];
        half4v nh;
        #pragma unroll
        for (int p = 0; p < 4; ++p)
          nh[p] = (_Float16)((float)oh[p] + acc2[mt][nt][p] + ((const float*)&bb)[p]);
        *(half4v*)&hA[row][feat0] = nh;
      }
    }
    __syncthreads();
  }

  // ---- GEMM3': cw' = Wout^T @ h^T (+bout+cb+xhat), then distance ----
  floatx4 acc3[4][4];
  #pragma unroll
  for (int mt = 0; mt < 4; ++mt)
    #pragma unroll
    for (int nt = 0; nt < 4; ++nt) acc3[mt][nt] = zero4;

  const _Float16* wo_b = woutf + (wave * 4) * 512 + lane8;
  __builtin_amdgcn_s_setprio(1);
  #pragma unroll 2
  for (int ks = 0; ks < 8; ++ks) {
    half8 b0 = *(const half8*)&hA[col][ks * 32 + quad * 8];
    half8 b1v = *(const half8*)&hA[16 + col][ks * 32 + quad * 8];
    half8 b2v = *(const half8*)&hA[32 + col][ks * 32 + quad * 8];
    half8 b3v = *(const half8*)&hA[48 + col][ks * 32 + quad * 8];
    const int ko = ks * 16 * 512;
    #pragma unroll
    for (int mt = 0; mt < 4; ++mt) {
      half8 aw = *(const half8*)(wo_b + ko + mt * 512);
      acc3[mt][0] = MFMAH(aw, b0, acc3[mt][0]);
      acc3[mt][1] = MFMAH(aw, b1v, acc3[mt][1]);
      acc3[mt][2] = MFMAH(aw, b2v, acc3[mt][2]);
      acc3[mt][3] = MFMAH(aw, b3v, acc3[mt][3]);
    }
  }
  __builtin_amdgcn_s_setprio(0);

  float s[4] = {0.f, 0.f, 0.f, 0.f};
  #pragma unroll
  for (int mt = 0; mt < 4; ++mt) {
    const int d0 = (wave * 4 + mt) * 16 + quad * 4;
    float4 bo = *(const float4*)&bout[d0];
    float4 xv = *(const float4*)&x_s[d0];
    float4 xh4 = *(const float4*)&xh_s[d0];
    #pragma unroll
    for (int nt = 0; nt < 4; ++nt) {
      float4 cbv = *(const float4*)&cb[(k0 + nt * 16 + col) * D_ + d0];
      #pragma unroll
      for (int p = 0; p < 4; ++p) {
        float base = ((const float*)&bo)[p] + ((const float*)&xh4)[p];
        float xx = ((const float*)&xv)[p];
        float cw = acc3[mt][nt][p] + base + ((const float*)&cbv)[p];
        s[nt] += cw * (cw - 2.f * xx);   // -||x||^2 const: argmin-invariant
      }
    }
  }
  #pragma unroll
  for (int nt = 0; nt < 4; ++nt) {
    s[nt] += __shfl_xor(s[nt], 16, 64);
    s[nt] += __shfl_xor(s[nt], 32, 64);
  }
  if (quad == 0) {
    #pragma unroll
    for (int nt = 0; nt < 4; ++nt)
      dist_s[wave][nt * 16 + col] = s[nt];
  }
  __syncthreads();
  if (t < 64) {
    float d = dist_s[0][t] + dist_s[1][t] + dist_s[2][t] + dist_s[3][t];
    dists[b * (F_ * K_) + f * K_ + k0 + t] = d;
  }
}

// ---------------------------------------------------------------------------
// top-8: wave-level shfl_xor (val,idx) butterfly — 2 barriers/pass.
__global__ void k_top8(const float* __restrict__ dists, int* __restrict__ topi) {
  __shared__ float ds[F_ * K_];
  __shared__ float wv[8];
  __shared__ int   wi[8];
  const int b = blockIdx.x, t = threadIdx.x;
  const int wave = t >> 6, lane = t & 63;
  for (int j = t; j < F_ * K_; j += 512) ds[j] = dists[b * (F_ * K_) + j];
  __syncthreads();
  for (int pass = 0; pass < 8; ++pass) {
    float best = 3.4e38f; int bi = 0;
    #pragma unroll
    for (int j = t; j < F_ * K_; j += 512) {
      const float dv = ds[j];
      if (dv < best) { best = dv; bi = j; }
    }
    #pragma unroll
    for (int off = 1; off < 64; off <<= 1) {
      const float ov = __shfl_xor(best, off, 64);
      const int oi = __shfl_xor(bi, off, 64);
      if (ov < best || (ov == best && oi < bi)) { best = ov; bi = oi; }
    }
    if (lane == 0) { wv[wave] = best; wi[wave] = bi; }
    __syncthreads();
    if (t == 0) {
      float bv2 = wv[0]; int bi2 = wi[0];
      #pragma unroll
      for (int w = 1; w < 8; ++w)
        if (wv[w] < bv2 || (wv[w] == bv2 && wi[w] < bi2)) { bv2 = wv[w]; bi2 = wi[w]; }
      topi[b * 8 + pass] = bi2;
      ds[bi2] = 3.4e38f;
    }
    __syncthreads();
  }
}

// ---------------------------------------------------------------------------
// Exact rescore, 256 blocks x 512 threads (R15/R22 verified; unroll 4).
#define NCL 2
__global__ __launch_bounds__(512) void k_resfin(
    const float* __restrict__ u, const float* __restrict__ v,
    const float* __restrict__ W1, const float* __restrict__ b1,
    const float* __restrict__ W2, const float* __restrict__ b2,
    const float* __restrict__ Wout, const float* __restrict__ bout,
    const float* __restrict__ cb, const float* __restrict__ xhat,
    const float* __restrict__ x, const int* __restrict__ topi,
    float* __restrict__ resc2, int* __restrict__ iwin2,
    float* __restrict__ cwhalf) {
  __shared__ float hs4[4][H_ + 4];      // 4160 B (rows 16B-aligned)
  __shared__ float hms4[4][HFF_ + 4];   // 8256 B
  __shared__ float cw4[4][H_ + 4];      // 4160 B
  __shared__ float redw[8][NCL];
  __shared__ int   sel_sh;

  const int blk = blockIdx.x;
  const int b = blk >> 1, half = blk & 1;
  const int t = threadIdx.x;
  const int g = t >> 8, tloc = t & 255;
  const int wave = t >> 6, lane = t & 63;
  const int cbase = half * 4;

  int kc[NCL], bfc[NCL];
  #pragma unroll
  for (int cl = 0; cl < NCL; ++cl) {
    const int ix = topi[b * 8 + cbase + g * 2 + cl];
    kc[cl] = ix & 255;
    bfc[cl] = b * F_ + (ix >> 8);
  }

  #pragma unroll
  for (int cl = 0; cl < NCL; ++cl)
    hs4[g * 2 + cl][tloc] = u[kc[cl] * H_ + tloc] + v[bfc[cl] * H_ + tloc];
  __syncthreads();

  #pragma unroll 1
  for (int l = 0; l < 2; ++l) {
    const float* W1l = W1 + l * (H_ * HFF_);
    const float* W2l = W2 + l * (HFF_ * H_);

    float a0[NCL], a1[NCL];
    {
      const float bb0 = b1[l * HFF_ + tloc], bb1 = b1[l * HFF_ + 256 + tloc];
      #pragma unroll
      for (int cl = 0; cl < NCL; ++cl) { a0[cl] = bb0; a1[cl] = bb1; }
    }
    #pragma unroll 4
    for (int i = 0; i < H_; i += 4) {
      float4 hv[NCL];
      #pragma unroll
      for (int cl = 0; cl < NCL; ++cl) hv[cl] = *(const float4*)&hs4[g * 2 + cl][i];
      #pragma unroll
      for (int q = 0; q < 4; ++q) {
        const float w0 = W1l[(i + q) * HFF_ + tloc];
        const float w1 = W1l[(i + q) * HFF_ + 256 + tloc];
        #pragma unroll
        for (int cl = 0; cl < NCL; ++cl) {
          const float h = ((const float*)&hv[cl])[q];
          a0[cl] = fmaf(h, w0, a0[cl]);
          a1[cl] = fmaf(h, w1, a1[cl]);
        }
      }
    }
    #pragma unroll
    for (int cl = 0; cl < NCL; ++cl) {
      hms4[g * 2 + cl][tloc] = fmaxf(a0[cl], 0.f);
      hms4[g * 2 + cl][tloc + 256] = fmaxf(a1[cl], 0.f);
    }
    __syncthreads();

    float hn[NCL];
    {
      const float bb2 = b2[l * H_ + tloc];
      #pragma unroll
      for (int cl = 0; cl < NCL; ++cl) hn[cl] = hs4[g * 2 + cl][tloc] + bb2;
    }
    #pragma unroll 4
    for (int jj = 0; jj < HFF_; jj += 4) {
      float4 hv[NCL];
      #pragma unroll
      for (int cl = 0; cl < NCL; ++cl) hv[cl] = *(const float4*)&hms4[g * 2 + cl][jj];
      #pragma unroll
      for (int q = 0; q < 4; ++q) {
        const float w = W2l[(jj + q) * H_ + tloc];
        #pragma unroll
        for (int cl = 0; cl < NCL; ++cl)
          hn[cl] = fmaf(((const float*)&hv[cl])[q], w, hn[cl]);
      }
    }
    __syncthreads();
    #pragma unroll
    for (int cl = 0; cl < NCL; ++cl) hs4[g * 2 + cl][tloc] = hn[cl];
    __syncthreads();
  }

  float cw[NCL];
  {
    const float bo = bout[tloc];
    #pragma unroll
    for (int cl = 0; cl < NCL; ++cl)
      cw[cl] = bo + cb[kc[cl] * D_ + tloc] + xhat[bfc[cl] * D_ + tloc];
  }
  #pragma unroll 4
  for (int i = 0; i < H_; i += 4) {
    float4 hv[NCL];
    #pragma unroll
    for (int cl = 0; cl < NCL; ++cl) hv[cl] = *(const float4*)&hs4[g * 2 + cl][i];
    #pragma unroll
    for (int q = 0; q < 4; ++q) {
      const float w = Wout[(i + q) * D_ + tloc];
      #pragma unroll
      for (int cl = 0; cl < NCL; ++cl)
        cw[cl] = fmaf(((const float*)&hv[cl])[q], w, cw[cl]);
    }
  }

  const float xx = x[b * D_ + tloc];
  #pragma unroll
  for (int cl = 0; cl < NCL; ++cl) {
    cw4[g * 2 + cl][tloc] = cw[cl];
    float vsum = cw[cl] * (cw[cl] - 2.f * xx);
    vsum += __shfl_xor(vsum, 1, 64);
    vsum += __shfl_xor(vsum, 2, 64);
    vsum += __shfl_xor(vsum, 4, 64);
    vsum += __shfl_xor(vsum, 8, 64);
    vsum += __shfl_xor(vsum, 16, 64);
    vsum += __shfl_xor(vsum, 32, 64);
    if (lane == 0) redw[wave][cl] = vsum;
  }
  __syncthreads();
  if (t == 0) {
    float bd = 3.4e38f; int bidx = 1 << 30; int bc = 0;
    #pragma unroll
    for (int c = 0; c < 4; ++c) {
      const int gg = c >> 1, cl = c & 1;
      const float d = redw[gg * 4 + 0][cl] + redw[gg * 4 + 1][cl] +
                      redw[gg * 4 + 2][cl] + redw[gg * 4 + 3][cl];
      const int ix = topi[b * 8 + cbase + c];
      if (d < bd || (d == bd && ix < bidx)) { bd = d; bidx = ix; bc = c; }
    }
    resc2[blk] = bd;
    iwin2[blk] = bidx;
    sel_sh = bc;
  }
  __syncthreads();
  if (t < 256) cwhalf[blk * 256 + t] = cw4[sel_sh][t];
}

// ---------------------------------------------------------------------------
// Combine the two halves' winners; write output.
__global__ void k_finw(const float* __restrict__ resc2, const int* __restrict__ iwin2,
                       const float* __restrict__ cwhalf, const int* __restrict__ codes,
                       float* __restrict__ out) {
  const int b = blockIdx.x, t = threadIdx.x;
  const float d0 = resc2[b * 2], d1 = resc2[b * 2 + 1];
  const int i0 = iwin2[b * 2], i1 = iwin2[b * 2 + 1];
  const int sel = (d1 < d0 || (d1 == d0 && i1 < i0)) ? 1 : 0;
  out[b * D_ + t] = cwhalf[(b * 2 + sel) * 256 + t];
  if (t < 2)
    out[B_ * D_ + t * B_ + b] = (float)codes[t * B_ + b];
  else if (t == 2)
    out[B_ * D_ + 2 * B_ + b] = (float)(sel ? i1 : i0);
}

// ---------------------------------------------------------------------------
extern "C" void kernel_launch(void* const* d_in, const int* in_sizes, int n_in,
                              void* d_out, int out_size, void* d_ws, size_t ws_size,
                              hipStream_t stream) {
  const float* x    = (const float*)d_in[0];
  const float* xhat = (const float*)d_in[1];
  const int*   codes= (const int*)d_in[2];
  const float* cb   = (const float*)d_in[3];
  const float* Win  = (const float*)d_in[4];
  const float* bin  = (const float*)d_in[5];
  const float* Wcat = (const float*)d_in[6];
  const float* bcat = (const float*)d_in[7];
  const float* W1   = (const float*)d_in[8];
  const float* b1   = (const float*)d_in[9];
  const float* W2   = (const float*)d_in[10];
  const float* b2   = (const float*)d_in[11];
  const float* Wout = (const float*)d_in[12];
  const float* bout = (const float*)d_in[13];
  float* out = (float*)d_out;

  float* u     = (float*)d_ws;                  // 65536 f (h0 eliminated)
  float* v     = u + K_ * H_;                   // 262144 f
  float* dists = v + B_ * F_ * H_;              // 262144 f
  float* resc  = dists + B_ * F_ * K_;          // 1024 f
  int*   topi  = (int*)(resc + 1024);           // 1024 i
  int*   pad   = topi + 1024;                   // 128 pad (keeps 16B align)
  _Float16* w1f  = (_Float16*)(pad + 128);      // 2*H*HFF halves
  _Float16* w2f  = w1f + 2 * H_ * HFF_;
  _Float16* wof  = w2f + 2 * HFF_ * H_;
  _Float16* pre_u = wof + H_ * D_;              // 256*512 halves
  _Float16* pre_v = pre_u + K_ * HFF_;          // 1024*512 halves

  float* resc2  = resc;
  int*   iwin2  = (int*)(resc + 256);
  float* cwhalf = dists;

  k_prep<<<K_ + B_ * F_ + 2304, 256, 0, stream>>>(cb, Win, bin, Wcat, bcat, xhat,
                                                  W1, b1, W2, Wout, u, v,
                                                  w1f, w2f, wof, pre_u, pre_v);

  k_main<<<B_ * F_ * (K_ / RT), 256, 0, stream>>>(u, v, w1f, b1, w2f, b2,
                                                  wof, bout, cb, xhat, x,
                                                  pre_u, pre_v, dists);
  k_top8<<<B_, 512, 0, stream>>>(dists, topi);
  k_resfin<<<2 * B_, 512, 0, stream>>>(u, v, W1, b1, W2, b2, Wout, bout, cb, xhat,
                                       x, topi, resc2, iwin2, cwhalf);
  k_finw<<<B_, 256, 0, stream>>>(resc2, iwin2, cwhalf, codes, out);
}